// Round 5
// baseline (2169.082 us; speedup 1.0000x reference)
//
#include <hip/hip_runtime.h>

// DNAMite GAM on MI355X. Round 5 structure:
//  - W1 in LDS (f16, XOR-swizzled), staged column-per-thread (8-way max
//    conflicts instead of 32-way).
//  - A-fragments and GEMM0 B-fragments loaded directly from global (emb/W0
//    are L1/L2-hot) — no sA/sW0 in LDS. LDS 49 KB -> 3 blocks/CU.
//  - 2 barriers per tile; cross-wave y-reduction folded into next tile's
//    barrier. One plain write per (g,b) to ws, tree-reduced after.

typedef _Float16 f16x8 __attribute__((ext_vector_type(8)));
typedef _Float16 f16x2 __attribute__((ext_vector_type(2)));
typedef float f32x4 __attribute__((ext_vector_type(4)));

constexpr int Bsz = 512;
constexpr int NF  = 64;
constexpr int NE  = 32;
constexpr int NH  = 128;
constexpr int NP  = 2016;
constexpr int NG  = NP + NF;       // 2080 groups = grid
constexpr int BT  = 64;            // batch tile
constexpr int NSEG = 32, GSEG = NG / NSEG;  // 65

// ws layout (floats): [NG*Bsz] partials | [NSEG*Bsz] stage2 | pairsT ints
constexpr size_t WS_S2 = (size_t)NG * Bsz;
constexpr size_t WS_PT = WS_S2 + (size_t)NSEG * Bsz;

__device__ __forceinline__ float smoothz(float z) {
  float s = fmaf(-2.0f * z * z, z, fmaf(1.5f, z, 0.5f));
  if (z <= -0.5f) s = 0.0f;
  if (z >=  0.5f) s = 1.0f;
  return s;
}

__device__ __forceinline__ f16x8 to_f16x8(float4 a, float4 b) {
  f16x8 h;
  h[0] = (_Float16)a.x; h[1] = (_Float16)a.y;
  h[2] = (_Float16)a.z; h[3] = (_Float16)a.w;
  h[4] = (_Float16)b.x; h[5] = (_Float16)b.y;
  h[6] = (_Float16)b.z; h[7] = (_Float16)b.w;
  return h;
}

// [512][4032] -> [4032][512] int transpose, LDS-tiled 32x32.
__global__ void transpose_pairs_kernel(const int* __restrict__ pairs,
                                       int* __restrict__ pt) {
  __shared__ int tile[32][33];
  const int bt = blockIdx.x;
  const int qt = blockIdx.y;
  const int t  = threadIdx.x;
  const int tq = t & 7, tb = t >> 3;
  const int brow  = bt * 32 + tb;
  const int qbase = qt * 32 + tq * 4;
#pragma unroll
  for (int j = 0; j < 4; ++j)
    tile[tb][tq * 4 + j] = pairs[brow * (2 * NP) + qbase + j];
  __syncthreads();
  const int ob = t & 7, oq = t >> 3;
  const int qrow = qt * 32 + oq;
#pragma unroll
  for (int j = 0; j < 4; ++j)
    pt[(size_t)qrow * Bsz + bt * 32 + ob * 4 + j] = tile[ob * 4 + j][oq];
}

__global__ __launch_bounds__(256, 3) void fused_groups_kernel(
    const int* __restrict__ mains, const int* __restrict__ pt,
    const float* __restrict__ emb,
    const float* __restrict__ mw0, const float* __restrict__ mw1,
    const float* __restrict__ mw2, const float* __restrict__ mb0,
    const float* __restrict__ mb1, const float* __restrict__ mb2,
    const float* __restrict__ z_main,
    const float* __restrict__ pw0, const float* __restrict__ pw1,
    const float* __restrict__ pw2, const float* __restrict__ pb0,
    const float* __restrict__ pb1, const float* __restrict__ pb2,
    const float* __restrict__ z_pairs,
    const int* __restrict__ pairs_list, const int* __restrict__ foff,
    float* __restrict__ ws) {
  // sW1: [col][k] f16, swizzled: halfword addr = c*128 + ((k>>3)^(c&7))*8 + (k&7)
  __shared__ _Float16 sW1[NH * NH];   // 32 KB
  __shared__ _Float16 sH[BT * NH];    // 16 KB, same layout with row as c
  __shared__ float    sRed[4 * BT];   // 1 KB

  const int t    = threadIdx.x;
  const int wave = t >> 6;
  const int lane = t & 63;
  const int l    = lane & 15;
  const int qd   = lane >> 4;
  const int wnb  = wave * 32;
  const int g    = blockIdx.x;
  const bool is_pair = (g < NP);

  const float *W0, *W1, *w2p, *bv0, *bv1;
  float b2s, z;
  int kc0, off0 = 0, off1 = 0, fid = 0;
  if (is_pair) {
    W0  = pw0 + (size_t)g * (2 * NE * NH);
    W1  = pw1 + (size_t)g * (NH * NH);
    w2p = pw2 + (size_t)g * NH;
    bv0 = pb0 + (size_t)g * NH;
    bv1 = pb1 + (size_t)g * NH;
    b2s = pb2[g];
    z   = smoothz(z_pairs[g]);
    kc0 = 2;
    off0 = foff[pairs_list[2 * g + 0]];
    off1 = foff[pairs_list[2 * g + 1]];
  } else {
    fid = g - NP;
    W0  = mw0 + (size_t)fid * (NE * NH);
    W1  = mw1 + (size_t)fid * (NH * NH);
    w2p = mw2 + (size_t)fid * NH;
    bv0 = mb0 + (size_t)fid * NH;
    bv1 = mb1 + (size_t)fid * NH;
    b2s = mb2[fid];
    z   = smoothz(z_main[fid]);
    kc0 = 1;
    off0 = foff[fid];
  }

  // Per-lane bias / w2 for this lane's two output columns.
  float b0v[2], b1v[2], wv2[2];
#pragma unroll
  for (int nc = 0; nc < 2; ++nc) {
    const int col = wnb + nc * 16 + l;
    b0v[nc] = bv0[col];
    b1v[nc] = bv1[col];
    wv2[nc] = w2p[col];
  }

  // ---- stage W1 into LDS: one column per thread, packed f16x2 writes ----
  {
    const int c  = t & 127;
    const int kh = (t >> 7) * 64;
    const int cs = c & 7;
#pragma unroll 8
    for (int kk = 0; kk < 64; kk += 2) {
      const int k = kh + kk;
      const float a = W1[(size_t)k * NH + c];
      const float b = W1[(size_t)(k + 1) * NH + c];
      f16x2 p; p[0] = (_Float16)a; p[1] = (_Float16)b;
      *(f16x2*)&sW1[c * NH + (((k >> 3) ^ cs) * 8) + (k & 7)] = p;
    }
  }

  const int col0 = wnb + l, col1 = wnb + 16 + l;
  const int cs0 = (col0 & 7), cs1 = (col1 & 7);

  for (int tile = 0; tile < Bsz / BT; ++tile) {
    const int bbase = tile * BT;

    // ---- load A-fragments (global; emb is L2-hot) ----
    f16x8 af[4][2];
#pragma unroll
    for (int m = 0; m < 4; ++m) {
      const int b = bbase + m * 16 + l;
      if (is_pair) {
        const int bin0 = pt[(size_t)(2 * g + 0) * Bsz + b];
        const int bin1 = pt[(size_t)(2 * g + 1) * Bsz + b];
        const float* e0 = emb + (size_t)(bin0 + off0) * NE + qd * 8;
        const float* e1 = emb + (size_t)(bin1 + off1) * NE + qd * 8;
        af[m][0] = to_f16x8(((const float4*)e0)[0], ((const float4*)e0)[1]);
        af[m][1] = to_f16x8(((const float4*)e1)[0], ((const float4*)e1)[1]);
      } else {
        const int bin = mains[b * NF + fid];
        const float* e0 = emb + (size_t)(bin + off0) * NE + qd * 8;
        af[m][0] = to_f16x8(((const float4*)e0)[0], ((const float4*)e0)[1]);
      }
    }

    // ---- load GEMM0 B-fragments (global; W0 is L1-hot across tiles) ----
    f16x8 bf0[2][2];
    for (int kc = 0; kc < kc0; ++kc)
#pragma unroll
      for (int nc = 0; nc < 2; ++nc) {
        const float* p = W0 + (size_t)(kc * 32 + qd * 8) * NH + wnb + nc * 16 + l;
        f16x8 v;
#pragma unroll
        for (int j = 0; j < 8; ++j) v[j] = (_Float16)p[j * NH];
        bf0[kc][nc] = v;
      }

    __syncthreads();  // A: prior tile's sH reads + sRed writes complete

    // ---- flush previous tile's y to ws (folded into this barrier gap) ----
    if (tile > 0 && t < BT) {
      const float s =
          sRed[t] + sRed[BT + t] + sRed[2 * BT + t] + sRed[3 * BT + t];
      ws[(size_t)g * Bsz + (bbase - BT) + t] = (s + b2s) * z;
    }

    // ---- GEMM0: H1 = relu(E*W0 + b0) ----
    f32x4 acc0[4][2];
#pragma unroll
    for (int m = 0; m < 4; ++m)
#pragma unroll
      for (int nc = 0; nc < 2; ++nc)
        acc0[m][nc] = (f32x4){b0v[nc], b0v[nc], b0v[nc], b0v[nc]};

    for (int kc = 0; kc < kc0; ++kc)
#pragma unroll
      for (int m = 0; m < 4; ++m) {
        acc0[m][0] = __builtin_amdgcn_mfma_f32_16x16x32_f16(
            af[m][kc], bf0[kc][0], acc0[m][0], 0, 0, 0);
        acc0[m][1] = __builtin_amdgcn_mfma_f32_16x16x32_f16(
            af[m][kc], bf0[kc][1], acc0[m][1], 0, 0, 0);
      }

    // ---- relu + write H1 to sH (verified swizzle); D: row=qd*4+r, col=l ----
#pragma unroll
    for (int m = 0; m < 4; ++m)
#pragma unroll
      for (int nc = 0; nc < 2; ++nc)
#pragma unroll
        for (int r = 0; r < 4; ++r) {
          const float v = fmaxf(acc0[m][nc][r], 0.0f);
          const int row = m * 16 + qd * 4 + r;
          const int col = wnb + nc * 16 + l;
          sH[row * NH + (((col >> 3) ^ (row & 7)) * 8) + (col & 7)] =
              (_Float16)v;
        }
    __syncthreads();  // B: sH ready

    // ---- GEMM1: H2 = relu(H1*W1 + b1), A from sH, B from sW1 ----
    f32x4 acc1[4][2];
#pragma unroll
    for (int m = 0; m < 4; ++m)
#pragma unroll
      for (int nc = 0; nc < 2; ++nc)
        acc1[m][nc] = (f32x4){b1v[nc], b1v[nc], b1v[nc], b1v[nc]};

#pragma unroll
    for (int kc = 0; kc < 4; ++kc) {
      const int kb = kc * 4 + qd;
      const f16x8 bf0_ = *(const f16x8*)&sW1[col0 * NH + ((kb ^ cs0) * 8)];
      const f16x8 bf1_ = *(const f16x8*)&sW1[col1 * NH + ((kb ^ cs1) * 8)];
#pragma unroll
      for (int m = 0; m < 4; ++m) {
        const int brow = m * 16 + l;
        const f16x8 a_ = *(const f16x8*)&sH[brow * NH + ((kb ^ (brow & 7)) * 8)];
        acc1[m][0] = __builtin_amdgcn_mfma_f32_16x16x32_f16(a_, bf0_, acc1[m][0], 0, 0, 0);
        acc1[m][1] = __builtin_amdgcn_mfma_f32_16x16x32_f16(a_, bf1_, acc1[m][1], 0, 0, 0);
      }
    }

    // ---- layer 2: per-wave partial y over its 32 cols ----
    float v16[16];
#pragma unroll
    for (int m = 0; m < 4; ++m)
#pragma unroll
      for (int r = 0; r < 4; ++r)
        v16[m * 4 + r] = fmaf(fmaxf(acc1[m][0][r], 0.0f), wv2[0],
                              fmaxf(acc1[m][1][r], 0.0f) * wv2[1]);

    const int lb0 = l & 1, lb1 = (l >> 1) & 1, lb2 = (l >> 2) & 1,
              lb3 = (l >> 3) & 1;
    float v8[8];
#pragma unroll
    for (int i = 0; i < 8; ++i) {
      const float mine   = lb0 ? v16[2 * i + 1] : v16[2 * i];
      const float theirs = lb0 ? v16[2 * i]     : v16[2 * i + 1];
      v8[i] = mine + __shfl_xor(theirs, 1, 64);
    }
    float v4[4];
#pragma unroll
    for (int i = 0; i < 4; ++i) {
      const float mine   = lb1 ? v8[2 * i + 1] : v8[2 * i];
      const float theirs = lb1 ? v8[2 * i]     : v8[2 * i + 1];
      v4[i] = mine + __shfl_xor(theirs, 2, 64);
    }
    float v2[2];
#pragma unroll
    for (int i = 0; i < 2; ++i) {
      const float mine   = lb2 ? v4[2 * i + 1] : v4[2 * i];
      const float theirs = lb2 ? v4[2 * i]     : v4[2 * i + 1];
      v2[i] = mine + __shfl_xor(theirs, 4, 64);
    }
    const float mine1   = lb3 ? v2[1] : v2[0];
    const float theirs1 = lb3 ? v2[0] : v2[1];
    const float v1 = mine1 + __shfl_xor(theirs1, 8, 64);

    // stash per-wave partial; flushed after the NEXT barrier (or at end)
    const int row_local = (l >> 2) * 16 + qd * 4 + (l & 3);
    sRed[wave * BT + row_local] = v1;
  }

  __syncthreads();
  if (t < BT) {
    const float s =
        sRed[t] + sRed[BT + t] + sRed[2 * BT + t] + sRed[3 * BT + t];
    ws[(size_t)g * Bsz + (Bsz - BT) + t] = (s + b2s) * z;
  }
}

__global__ void reduce1_kernel(const float* __restrict__ part,
                               float* __restrict__ s2) {
  const int b   = blockIdx.x * 256 + threadIdx.x;
  const int seg = blockIdx.y;
  float s = 0.0f;
#pragma unroll 8
  for (int g = seg * GSEG; g < (seg + 1) * GSEG; ++g)
    s += part[(size_t)g * Bsz + b];
  s2[seg * Bsz + b] = s;
}

__global__ void reduce2_kernel(const float* __restrict__ s2,
                               float* __restrict__ out) {
  const int b = blockIdx.x * 256 + threadIdx.x;
  float s = 0.0f;
#pragma unroll
  for (int k = 0; k < NSEG; ++k) s += s2[k * Bsz + b];
  out[b] = s;
}

extern "C" void kernel_launch(void* const* d_in, const int* in_sizes, int n_in,
                              void* d_out, int out_size, void* d_ws,
                              size_t ws_size, hipStream_t stream) {
  const int*   mains      = (const int*)d_in[0];
  const int*   pairs      = (const int*)d_in[1];
  const float* emb        = (const float*)d_in[2];
  const float* mw0        = (const float*)d_in[3];
  const float* mw1        = (const float*)d_in[4];
  const float* mw2        = (const float*)d_in[5];
  const float* mb0        = (const float*)d_in[6];
  const float* mb1        = (const float*)d_in[7];
  const float* mb2        = (const float*)d_in[8];
  const float* z_main     = (const float*)d_in[9];
  const float* pw0        = (const float*)d_in[10];
  const float* pw1        = (const float*)d_in[11];
  const float* pw2        = (const float*)d_in[12];
  const float* pb0        = (const float*)d_in[13];
  const float* pb1        = (const float*)d_in[14];
  const float* pb2        = (const float*)d_in[15];
  const float* z_pairs    = (const float*)d_in[16];
  const int*   pairs_list = (const int*)d_in[17];
  const int*   foff       = (const int*)d_in[18];
  float* ws   = (float*)d_ws;
  float* out  = (float*)d_out;
  float* part = ws;
  float* s2   = ws + WS_S2;
  int*   pt   = (int*)(ws + WS_PT);

  transpose_pairs_kernel<<<dim3(16, 126), 256, 0, stream>>>(pairs, pt);
  fused_groups_kernel<<<NG, 256, 0, stream>>>(
      mains, pt, emb, mw0, mw1, mw2, mb0, mb1, mb2, z_main, pw0, pw1, pw2,
      pb0, pb1, pb2, z_pairs, pairs_list, foff, part);
  reduce1_kernel<<<dim3(2, NSEG), 256, 0, stream>>>(part, s2);
  reduce2_kernel<<<2, 256, 0, stream>>>(s2, out);
}